// Round 1
// baseline (181.255 us; speedup 1.0000x reference)
//
#include <hip/hip_runtime.h>

// LIF layer fused step, f32.
// Inputs (setup_inputs order):
//   d_in[0] input_spikes [8192]      f32
//   d_in[1] voltages     [1, 8192]   f32
//   d_in[2] synapses     [8192,8192] f32
//   d_in[3] weights      [8192,8192] f32
// Outputs (return order, concatenated flat in d_out, f32):
//   [0 .. 8192)            spikes (bool -> 0.0/1.0)
//   [8192 .. 16384)        v_new
//   [16384 .. 16384+64M)   syn

#define V_DECAY 0.99004983374916811f   // exp(-1/100), rounded to f32 like jax
#define S_DECAY 0.98019867330675525f   // exp(-1/50)
#define THRESH  1.0f

constexpr int N_IN  = 8192;
constexpr int N_OUT = 8192;
constexpr int COLS_PER_BLOCK = 1024;            // 256 threads x float4
constexpr int COL_TILES = N_OUT / COLS_PER_BLOCK;  // 8

// Kernel 1: syn = synapses*S_DECAY + weights*spike_row; write syn; emit
// per-(row-chunk, column) partial sums into d_ws (deterministic reduction).
__global__ __launch_bounds__(256) void lif_syn_kernel(
    const float* __restrict__ input_spikes,
    const float* __restrict__ synapses,
    const float* __restrict__ weights,
    float* __restrict__ syn_out,
    float* __restrict__ partials,       // [rowChunks][N_OUT]
    int rowsPerChunk)
{
    const int ct   = blockIdx.x % COL_TILES;
    const int rc   = blockIdx.x / COL_TILES;
    const int col  = ct * COLS_PER_BLOCK + threadIdx.x * 4;
    const int row0 = rc * rowsPerChunk;

    float4 acc = make_float4(0.f, 0.f, 0.f, 0.f);
    for (int r = 0; r < rowsPerChunk; ++r) {
        const int row   = row0 + r;
        const size_t idx = (size_t)row * N_OUT + col;
        const float4 s4 = *reinterpret_cast<const float4*>(synapses + idx);
        const float4 w4 = *reinterpret_cast<const float4*>(weights  + idx);
        const float  sp = input_spikes[row];   // block-uniform, L1/L2-cached
        float4 o;
        o.x = s4.x * S_DECAY + w4.x * sp;
        o.y = s4.y * S_DECAY + w4.y * sp;
        o.z = s4.z * S_DECAY + w4.z * sp;
        o.w = s4.w * S_DECAY + w4.w * sp;
        *reinterpret_cast<float4*>(syn_out + idx) = o;
        acc.x += o.x; acc.y += o.y; acc.z += o.z; acc.w += o.w;
    }
    *reinterpret_cast<float4*>(partials + (size_t)rc * N_OUT + col) = acc;
}

// Kernel 2: reduce partials per column, compute spike + v_new.
__global__ __launch_bounds__(256) void lif_v_kernel(
    const float* __restrict__ voltages,
    const float* __restrict__ partials,
    float* __restrict__ out,            // out[0..N_OUT)=spikes, [N_OUT..2N)=v_new
    int rowChunks)
{
    const int c = blockIdx.x * blockDim.x + threadIdx.x;
    const float v     = voltages[c] * V_DECAY;
    const float spike = (v >= THRESH) ? 1.0f : 0.0f;
    float sum = 0.f;
    for (int rc = 0; rc < rowChunks; ++rc)
        sum += partials[(size_t)rc * N_OUT + c];   // coalesced across threads
    out[c]          = spike;
    out[N_OUT + c]  = v + sum - spike * THRESH;
}

extern "C" void kernel_launch(void* const* d_in, const int* in_sizes, int n_in,
                              void* d_out, int out_size, void* d_ws, size_t ws_size,
                              hipStream_t stream) {
    const float* input_spikes = (const float*)d_in[0];
    const float* voltages     = (const float*)d_in[1];
    const float* synapses     = (const float*)d_in[2];
    const float* weights      = (const float*)d_in[3];

    float* out      = (float*)d_out;
    float* syn_out  = out + 2 * N_OUT;
    float* partials = (float*)d_ws;

    // Pick the largest power-of-two row-chunk count whose partial buffer fits d_ws.
    int rowChunks = 128;                                   // 4 MB preferred
    while (rowChunks > 1 &&
           (size_t)rowChunks * N_OUT * sizeof(float) > ws_size)
        rowChunks >>= 1;
    const int rowsPerChunk = N_IN / rowChunks;

    lif_syn_kernel<<<dim3(COL_TILES * rowChunks), dim3(256), 0, stream>>>(
        input_spikes, synapses, weights, syn_out, partials, rowsPerChunk);

    lif_v_kernel<<<dim3(N_OUT / 256), dim3(256), 0, stream>>>(
        voltages, partials, out, rowChunks);
}